// Round 1
// baseline (220.549 us; speedup 1.0000x reference)
//
#include <hip/hip_runtime.h>
#include <math.h>

#define B_CONST 256
#define V_CONST 128000
#define L_CONST 200
#define SLICES 4

// ws layout: int gt[B], int sub[B], int distinct[B]
__global__ void zero_ws_kernel(int* __restrict__ ws) {
    int i = threadIdx.x;
    if (i < 3 * B_CONST) ws[i] = 0;
}

// grid: (SLICES, B), block: 256
__global__ __launch_bounds__(256) void rank_count_kernel(
    const float* __restrict__ scores,
    const int* __restrict__ labels,
    const int* __restrict__ seqs,
    int* __restrict__ gt,
    int* __restrict__ sub,
    int* __restrict__ distinct)
{
    const int b     = blockIdx.y;
    const int slice = blockIdx.x;
    const int tid   = threadIdx.x;

    const float* row = scores + (size_t)b * V_CONST;
    const int   label   = labels[b];
    const float predict = row[label];   // broadcast load, all lanes same addr

    __shared__ int s_cnt, s_sub, s_dist;
    if (tid == 0) { s_cnt = 0; s_sub = 0; s_dist = 0; }
    __syncthreads();

    // --- streaming count: scores[b,v] > predict over this slice ---
    const int f4_total = V_CONST / 4;          // 32000
    const int f4_per   = f4_total / SLICES;    // 8000
    const float4* row4 = (const float4*)row;
    const int begin = slice * f4_per;
    const int end   = begin + f4_per;
    int local = 0;
    for (int i = begin + tid; i < end; i += 256) {
        float4 v = row4[i];
        local += (v.x > predict) + (v.y > predict) + (v.z > predict) + (v.w > predict);
    }
    // wave64 shuffle reduce
    #pragma unroll
    for (int off = 32; off > 0; off >>= 1)
        local += __shfl_down(local, off, 64);
    if ((tid & 63) == 0) atomicAdd(&s_cnt, local);

    // --- history correction (slice 0 only): dedup + gather ---
    if (slice == 0 && tid < L_CONST) {
        const int* srow = seqs + b * L_CONST;
        const int s = srow[tid];
        bool first = true;
        for (int j = 0; j < tid; ++j) {
            if (srow[j] == s) { first = false; break; }
        }
        if (first) {
            atomicAdd(&s_dist, 1);
            if (row[s] > predict) atomicAdd(&s_sub, 1);
        }
    }
    __syncthreads();

    if (tid == 0) {
        atomicAdd(&gt[b], s_cnt);
        if (slice == 0) {
            atomicAdd(&sub[b], s_sub);
            atomicAdd(&distinct[b], s_dist);
        }
    }
}

// single block, 256 threads (one per row)
__global__ __launch_bounds__(256) void finalize_kernel(
    const int* __restrict__ gt,
    const int* __restrict__ sub,
    const int* __restrict__ distinct,
    float* __restrict__ out)
{
    const int b = threadIdx.x;
    const float rank  = (float)(gt[b] - sub[b]);
    const float valid = (float)(V_CONST - distinct[b]);

    const float ks[5] = {1.0f, 5.0f, 10.0f, 20.0f, 50.0f};
    float vals[12];
    const float invlog = 1.0f / log2f(rank + 2.0f);
    #pragma unroll
    for (int i = 0; i < 5; ++i) {
        const float ind = (rank < ks[i]) ? 1.0f : 0.0f;
        vals[2 * i]     = ind * invlog;   // NDCG@k
        vals[2 * i + 1] = ind;            // Recall@k
    }
    vals[10] = 1.0f / (rank + 1.0f);      // MRR
    vals[11] = 1.0f - rank / valid;       // AUC-like

    __shared__ float red[4];
    for (int q = 0; q < 12; ++q) {
        float v = vals[q];
        #pragma unroll
        for (int off = 32; off > 0; off >>= 1)
            v += __shfl_down(v, off, 64);
        if ((b & 63) == 0) red[b >> 6] = v;
        __syncthreads();
        if (b == 0) out[q] = (red[0] + red[1] + red[2] + red[3]) * (1.0f / B_CONST);
        __syncthreads();
    }
    if (b == 0) out[12] = 0.0f;
}

extern "C" void kernel_launch(void* const* d_in, const int* in_sizes, int n_in,
                              void* d_out, int out_size, void* d_ws, size_t ws_size,
                              hipStream_t stream) {
    const float* scores = (const float*)d_in[0];
    const int*   labels = (const int*)d_in[1];
    const int*   seqs   = (const int*)d_in[2];
    float* out = (float*)d_out;
    int*   ws  = (int*)d_ws;

    int* gt       = ws;
    int* sub      = ws + B_CONST;
    int* distinct = ws + 2 * B_CONST;

    zero_ws_kernel<<<1, 1024, 0, stream>>>(ws);
    rank_count_kernel<<<dim3(SLICES, B_CONST), 256, 0, stream>>>(
        scores, labels, seqs, gt, sub, distinct);
    finalize_kernel<<<1, 256, 0, stream>>>(gt, sub, distinct, out);
}

// Round 2
// 209.508 us; speedup vs baseline: 1.0527x; 1.0527x over previous
//
#include <hip/hip_runtime.h>
#include <math.h>

#define B_CONST 256
#define V_CONST 128000
#define L_CONST 200
#define SLICES  5
// f4 per row = 32000; per slice = 6400; per thread (256 thr) = 25 = 5 rounds x unroll-5

// ws layout: int partial[SLICES*B], int sub[B], int dist[B]  (all written unconditionally)

__global__ __launch_bounds__(256, 8) void rank_count_kernel(
    const float* __restrict__ scores,
    const int* __restrict__ labels,
    const int* __restrict__ seqs,
    int* __restrict__ partial,
    int* __restrict__ sub,
    int* __restrict__ dist)
{
    const int slice = blockIdx.x;
    const int b     = blockIdx.y;
    const int tid   = threadIdx.x;

    const float* row = scores + (size_t)b * V_CONST;
    const float predict = row[labels[b]];   // broadcast

    __shared__ int s_cnt, s_sub, s_dist;
    if (tid == 0) { s_cnt = 0; s_sub = 0; s_dist = 0; }
    __syncthreads();

    // --- streaming count over this slice: 5 rounds of 5 independent float4 loads ---
    const float4* row4 = (const float4*)row;
    int idx = slice * 6400 + tid;
    int cnt = 0;
    #pragma unroll
    for (int r = 0; r < 5; ++r) {
        float4 a0 = row4[idx];
        float4 a1 = row4[idx + 256];
        float4 a2 = row4[idx + 512];
        float4 a3 = row4[idx + 768];
        float4 a4 = row4[idx + 1024];
        cnt += (a0.x > predict) + (a0.y > predict) + (a0.z > predict) + (a0.w > predict);
        cnt += (a1.x > predict) + (a1.y > predict) + (a1.z > predict) + (a1.w > predict);
        cnt += (a2.x > predict) + (a2.y > predict) + (a2.z > predict) + (a2.w > predict);
        cnt += (a3.x > predict) + (a3.y > predict) + (a3.z > predict) + (a3.w > predict);
        cnt += (a4.x > predict) + (a4.y > predict) + (a4.z > predict) + (a4.w > predict);
        idx += 1280;
    }
    // wave64 shuffle reduce
    #pragma unroll
    for (int off = 32; off > 0; off >>= 1)
        cnt += __shfl_down(cnt, off, 64);
    if ((tid & 63) == 0) atomicAdd(&s_cnt, cnt);

    // --- history correction (slice 0 only): dedup + gather ---
    if (slice == 0 && tid < L_CONST) {
        const int* srow = seqs + b * L_CONST;
        const int s = srow[tid];
        bool first = true;
        for (int j = 0; j < tid; ++j) {
            if (srow[j] == s) { first = false; break; }
        }
        if (first) {
            atomicAdd(&s_dist, 1);
            if (row[s] > predict) atomicAdd(&s_sub, 1);
        }
    }
    __syncthreads();

    if (tid == 0) {
        partial[slice * B_CONST + b] = s_cnt;
        if (slice == 0) {
            sub[b]  = s_sub;
            dist[b] = s_dist;
        }
    }
}

// single block, 256 threads (one per row)
__global__ __launch_bounds__(256) void finalize_kernel(
    const int* __restrict__ partial,
    const int* __restrict__ sub,
    const int* __restrict__ dist,
    float* __restrict__ out)
{
    const int b = threadIdx.x;
    int gt = 0;
    #pragma unroll
    for (int s = 0; s < SLICES; ++s) gt += partial[s * B_CONST + b];
    const float rank  = (float)(gt - sub[b]);
    const float valid = (float)(V_CONST - dist[b]);

    const float ks[5] = {1.0f, 5.0f, 10.0f, 20.0f, 50.0f};
    float vals[12];
    const float invlog = 1.0f / log2f(rank + 2.0f);
    #pragma unroll
    for (int i = 0; i < 5; ++i) {
        const float ind = (rank < ks[i]) ? 1.0f : 0.0f;
        vals[2 * i]     = ind * invlog;   // NDCG@k
        vals[2 * i + 1] = ind;            // Recall@k
    }
    vals[10] = 1.0f / (rank + 1.0f);      // MRR
    vals[11] = 1.0f - rank / valid;       // AUC-like

    __shared__ float red[4];
    for (int q = 0; q < 12; ++q) {
        float v = vals[q];
        #pragma unroll
        for (int off = 32; off > 0; off >>= 1)
            v += __shfl_down(v, off, 64);
        if ((b & 63) == 0) red[b >> 6] = v;
        __syncthreads();
        if (b == 0) out[q] = (red[0] + red[1] + red[2] + red[3]) * (1.0f / B_CONST);
        __syncthreads();
    }
    if (b == 0) out[12] = 0.0f;
}

extern "C" void kernel_launch(void* const* d_in, const int* in_sizes, int n_in,
                              void* d_out, int out_size, void* d_ws, size_t ws_size,
                              hipStream_t stream) {
    const float* scores = (const float*)d_in[0];
    const int*   labels = (const int*)d_in[1];
    const int*   seqs   = (const int*)d_in[2];
    float* out = (float*)d_out;
    int*   ws  = (int*)d_ws;

    int* partial = ws;                          // SLICES*B
    int* sub     = ws + SLICES * B_CONST;       // B
    int* dist    = ws + SLICES * B_CONST + B_CONST;  // B

    rank_count_kernel<<<dim3(SLICES, B_CONST), 256, 0, stream>>>(
        scores, labels, seqs, partial, sub, dist);
    finalize_kernel<<<1, 256, 0, stream>>>(partial, sub, dist, out);
}

// Round 3
// 201.850 us; speedup vs baseline: 1.0926x; 1.0379x over previous
//
#include <hip/hip_runtime.h>
#include <math.h>

#define B_CONST 256
#define V_CONST 128000           // 32000 float4 per row
#define L_CONST 200
#define SLICES  25               // 1280 float4 per slice-block; 5 float4 per thread

// ws layout: int partial[SLICES*B], int sub[B], int dist[B]

__global__ __launch_bounds__(256) void rank_count_kernel(
    const float* __restrict__ scores,
    const int* __restrict__ labels,
    const int* __restrict__ seqs,
    int* __restrict__ partial,
    int* __restrict__ sub,
    int* __restrict__ dist)
{
    const int slice = blockIdx.x;
    const int b     = blockIdx.y;
    const int tid   = threadIdx.x;

    const float* row = scores + (size_t)b * V_CONST;

    // Issue the 5 independent streaming loads FIRST (before any barrier) so
    // they are in flight while we set up LDS.
    const float4* row4 = (const float4*)row;
    const int base = slice * 1280 + tid;     // f4 units
    float4 a0 = row4[base];
    float4 a1 = row4[base + 256];
    float4 a2 = row4[base + 512];
    float4 a3 = row4[base + 768];
    float4 a4 = row4[base + 1024];

    const float predict = row[labels[b]];    // broadcast

    __shared__ int s_cnt, s_sub, s_dist;
    __shared__ int s_seq[L_CONST];
    if (tid == 0) { s_cnt = 0; s_sub = 0; s_dist = 0; }
    if (slice == 0 && tid < L_CONST) s_seq[tid] = seqs[b * L_CONST + tid];
    __syncthreads();

    int cnt = 0;
    cnt += (a0.x > predict) + (a0.y > predict) + (a0.z > predict) + (a0.w > predict);
    cnt += (a1.x > predict) + (a1.y > predict) + (a1.z > predict) + (a1.w > predict);
    cnt += (a2.x > predict) + (a2.y > predict) + (a2.z > predict) + (a2.w > predict);
    cnt += (a3.x > predict) + (a3.y > predict) + (a3.z > predict) + (a3.w > predict);
    cnt += (a4.x > predict) + (a4.y > predict) + (a4.z > predict) + (a4.w > predict);

    // wave64 shuffle reduce
    #pragma unroll
    for (int off = 32; off > 0; off >>= 1)
        cnt += __shfl_down(cnt, off, 64);
    if ((tid & 63) == 0) atomicAdd(&s_cnt, cnt);

    // history correction (slice 0 only): dedup via LDS + gather
    if (slice == 0 && tid < L_CONST) {
        const int s = s_seq[tid];
        const float sv = row[s];             // issue gather early
        bool first = true;
        for (int j = 0; j < tid; ++j) {
            if (s_seq[j] == s) { first = false; break; }
        }
        if (first) {
            atomicAdd(&s_dist, 1);
            if (sv > predict) atomicAdd(&s_sub, 1);
        }
    }
    __syncthreads();

    if (tid == 0) {
        partial[slice * B_CONST + b] = s_cnt;
        if (slice == 0) {
            sub[b]  = s_sub;
            dist[b] = s_dist;
        }
    }
}

// single block, 256 threads (one per row)
__global__ __launch_bounds__(256) void finalize_kernel(
    const int* __restrict__ partial,
    const int* __restrict__ sub,
    const int* __restrict__ dist,
    float* __restrict__ out)
{
    const int b = threadIdx.x;
    int gt = 0;
    #pragma unroll
    for (int s = 0; s < SLICES; ++s) gt += partial[s * B_CONST + b];
    const float rank  = (float)(gt - sub[b]);
    const float valid = (float)(V_CONST - dist[b]);

    const float ks[5] = {1.0f, 5.0f, 10.0f, 20.0f, 50.0f};
    float vals[12];
    const float invlog = 1.0f / log2f(rank + 2.0f);
    #pragma unroll
    for (int i = 0; i < 5; ++i) {
        const float ind = (rank < ks[i]) ? 1.0f : 0.0f;
        vals[2 * i]     = ind * invlog;   // NDCG@k
        vals[2 * i + 1] = ind;            // Recall@k
    }
    vals[10] = 1.0f / (rank + 1.0f);      // MRR
    vals[11] = 1.0f - rank / valid;       // AUC-like

    __shared__ float red[4];
    for (int q = 0; q < 12; ++q) {
        float v = vals[q];
        #pragma unroll
        for (int off = 32; off > 0; off >>= 1)
            v += __shfl_down(v, off, 64);
        if ((b & 63) == 0) red[b >> 6] = v;
        __syncthreads();
        if (b == 0) out[q] = (red[0] + red[1] + red[2] + red[3]) * (1.0f / B_CONST);
        __syncthreads();
    }
    if (b == 0) out[12] = 0.0f;
}

extern "C" void kernel_launch(void* const* d_in, const int* in_sizes, int n_in,
                              void* d_out, int out_size, void* d_ws, size_t ws_size,
                              hipStream_t stream) {
    const float* scores = (const float*)d_in[0];
    const int*   labels = (const int*)d_in[1];
    const int*   seqs   = (const int*)d_in[2];
    float* out = (float*)d_out;
    int*   ws  = (int*)d_ws;

    int* partial = ws;                               // SLICES*B
    int* sub     = ws + SLICES * B_CONST;            // B
    int* dist    = ws + SLICES * B_CONST + B_CONST;  // B

    rank_count_kernel<<<dim3(SLICES, B_CONST), 256, 0, stream>>>(
        scores, labels, seqs, partial, sub, dist);
    finalize_kernel<<<1, 256, 0, stream>>>(partial, sub, dist, out);
}